// Round 2
// baseline (684.338 us; speedup 1.0000x reference)
//
#include <hip/hip_runtime.h>
#include <stdint.h>

typedef unsigned int u32;
typedef unsigned short u16;

#define NB 16
#define NL 4097      // x0 rows per batch (= att2 keys - 1)
#define NM_ROWS 1025 // x1 rows per batch
#define DS 256
#define DM 512
#define DL 1024
#define NK1 1025     // att1 keys
#define NK2 4098     // att2 keys
#define MPROJ 4098   // proj_w output dim

__device__ __forceinline__ float bf2f(u16 h){ union{u32 u; float f;} c; c.u = ((u32)h)<<16; return c.f; }
__device__ __forceinline__ u16 f2bf(float x){ union{float f; u32 u;} c; c.f=x; u32 u=c.u; return (u16)((u + 0x7fffu + ((u>>16)&1u))>>16); }
// dtype-flexible element read: f!=0 -> fp32, else bf16
__device__ __forceinline__ float getel(const void* p, long i, int f){
  return f ? ((const float*)p)[i] : bf2f(((const u16*)p)[i]);
}
__device__ __forceinline__ float wsum(float v){
  #pragma unroll
  for(int o=32;o>0;o>>=1) v += __shfl_xor(v,o,64);
  return v;
}
__device__ __forceinline__ float wmaxr(float v){
  #pragma unroll
  for(int o=32;o>0;o>>=1) v = fmaxf(v, __shfl_xor(v,o,64));
  return v;
}
__device__ __forceinline__ float block_sum(float v, volatile float* red){
  v = wsum(v);
  if((threadIdx.x&63)==0) red[threadIdx.x>>6]=v;
  __syncthreads();
  float r = red[0]+red[1]+red[2]+red[3];
  __syncthreads();
  return r;
}
__device__ __forceinline__ float block_max(float v, volatile float* red){
  v = wmaxr(v);
  if((threadIdx.x&63)==0) red[threadIdx.x>>6]=v;
  __syncthreads();
  float r = fmaxf(fmaxf(red[0],red[1]),fmaxf(red[2],red[3]));
  __syncthreads();
  return r;
}
__device__ __forceinline__ float clamp60(float x){ return fminf(fmaxf(x,-60.f),60.f); }

// ---- dtype detection: bf16 N(0,1) data -> max|bf16(u16)| ~ 5; fp32 bits read
// as u16 halves -> random low halves decode to huge bf16 values w.h.p.
__global__ __launch_bounds__(256) void detect_kernel(const u16* __restrict__ x0, int* __restrict__ flag){
  __shared__ float red[256];
  float mx=0.f;
  for(int i=threadIdx.x;i<4096;i+=256){
    float v = fabsf(bf2f(x0[i]));
    if (v==v) mx = fmaxf(mx, v);  // skip NaN
  }
  red[threadIdx.x]=mx; __syncthreads();
  if(threadIdx.x==0){
    float m=0.f;
    for(int i=0;i<256;i++) m=fmaxf(m,red[i]);
    flag[0] = (m>1e3f)?1:0;
  }
}

// ---- batched matvec: out[b,m] = bias[m] + sum_d W[m,d]*x[b,d] ----
// wave per m, 16 batches per wave. x staged in LDS in <=32KB chunks.
struct Job {
  const void* W; const void* x; const void* bias; float* out;
  int M, D; long xstride; int xinws;  // xinws: x is dense fp32 in ws
};

__global__ __launch_bounds__(256) void gemv_n_kernel(Job j0, Job j1, const int* __restrict__ flagp){
  Job j = (blockIdx.y==0)? j0 : j1;
  int f = flagp[0];
  __shared__ float xs[NB*512];
  int tid = threadIdx.x;
  int m = blockIdx.x*4 + (tid>>6);
  int l = tid & 63;
  float acc[NB];
  #pragma unroll
  for(int b=0;b<NB;b++) acc[b]=0.f;
  for(int c0=0;c0<j.D;c0+=512){
    int cl = j.D-c0; if (cl>512) cl=512;
    for(int i=tid;i<NB*cl;i+=256){
      int b=i/cl, d=i-b*cl;
      float v;
      if (j.xinws) v = ((const float*)j.x)[(long)b*j.D + c0 + d];
      else         v = getel(j.x, (long)b*j.xstride + c0 + d, f);
      xs[i]=v;
    }
    __syncthreads();
    if (m < j.M){
      for(int d=l; d<cl; d+=64){
        float w = getel(j.W, (long)m*j.D + c0 + d, f);
        #pragma unroll
        for(int b=0;b<NB;b++) acc[b] += w*xs[b*cl+d];
      }
    }
    __syncthreads();
  }
  if (m >= j.M) return;
  #pragma unroll
  for(int b=0;b<NB;b++) acc[b]=wsum(acc[b]);
  if(l==0){
    float bv = j.bias ? getel(j.bias, m, f) : 0.f;
    #pragma unroll
    for(int b=0;b<NB;b++) j.out[(long)b*j.M+m]=acc[b]+bv;
  }
}

// ---- transpose matvec: out[b,d] += sum_m W[m,d]*x[b,m]  (out pre-zeroed) ----
struct TJob { const void* W; const float* x; float* out; int M, D; };

__global__ __launch_bounds__(256) void gemv_t_kernel(TJob j0, TJob j1, const int* __restrict__ flagp){
  TJob j = (blockIdx.z==0)? j0 : j1;
  int f = flagp[0];
  if ((int)(blockIdx.x*256) >= j.D) return;   // block-uniform guards (before any barrier)
  int m0 = blockIdx.y*64;
  if (m0 >= j.M) return;
  __shared__ float xs[NB*64];
  int d = blockIdx.x*256 + threadIdx.x;
  for(int i=threadIdx.x;i<NB*64;i+=256){ int b=i>>6, mm=i&63; xs[i]=j.x[(long)b*j.M+m0+mm]; }
  __syncthreads();
  float acc[NB];
  #pragma unroll
  for(int b=0;b<NB;b++) acc[b]=0.f;
  for(int mm=0;mm<64;++mm){
    float w = getel(j.W, (long)(m0+mm)*j.D + d, f);
    #pragma unroll
    for(int b=0;b<NB;b++) acc[b] += w*xs[b*64+mm];
  }
  #pragma unroll
  for(int b=0;b<NB;b++) atomicAdd(&j.out[(long)b*j.D+d], acc[b]);
}

// ---- att1 logits for keys 1..1024 (p_m rows of x1): logits1[b,k] = q1p.x1row/22 ----
__global__ __launch_bounds__(256) void att1_logits_kernel(const void* __restrict__ x1,
    const float* __restrict__ q1p, float* __restrict__ logits1, const int* __restrict__ flagp){
  int f = flagp[0];
  int b = blockIdx.y;
  int k = blockIdx.x*4 + (threadIdx.x>>6) + 1;
  if (k > 1024) return;
  int l = threadIdx.x & 63;
  long rbase = ((long)b*NM_ROWS + k)*DM;
  float s = 0.f;
  for(int d=l; d<DM; d+=64)
    s += getel(x1, rbase+d, f) * q1p[(long)b*DM+d];
  s = wsum(s);
  if(l==0) logits1[(long)b*NK1 + k] = s * (1.f/22.f);
}

// ---- att1 softmax (one block per batch); key0 logit = q1p.cls_s_proj/22 ----
__global__ __launch_bounds__(256) void att1_softmax_kernel(const float* __restrict__ csp,
    const float* __restrict__ q1p, const float* __restrict__ logits1, float* __restrict__ att1_sm){
  __shared__ float red[4];
  int b=blockIdx.x, t=threadIdx.x;
  float p=0.f;
  for(int d=t;d<DM;d+=256) p += q1p[(long)b*DM+d]*csp[(long)b*DM+d];
  float l0 = block_sum(p, red) * (1.f/22.f);
  float mx = l0;
  for(int k=1+t;k<NK1;k+=256) mx = fmaxf(mx, logits1[(long)b*NK1+k]);
  mx = block_max(mx, red);
  float s=0.f;
  for(int k=t;k<NK1;k+=256){
    float lg = (k==0)? l0 : logits1[(long)b*NK1+k];
    float e = __expf(clamp60(lg-mx));
    att1_sm[(long)b*NK1+k]=e;
    s+=e;
  }
  s = block_sum(s, red);
  float inv = 1.f/fmaxf(s,1e-30f);
  for(int k=t;k<NK1;k+=256) att1_sm[(long)b*NK1+k]*=inv;
}

// ---- att1 projection: att1w[b,m] = 0.3*(proj_b[m] + sum_k att1_sm[b,k]*proj_w[m,k]) ----
__global__ __launch_bounds__(256) void att1_proj_kernel(const void* __restrict__ proj_w,
    const void* __restrict__ proj_b, const float* __restrict__ att1_sm, float* __restrict__ att1w,
    const int* __restrict__ flagp){
  int f = flagp[0];
  __shared__ float sm[8*1024];   // 32KB: 8 batches at a time
  int tid=threadIdx.x;
  int m = blockIdx.x*4 + (tid>>6);
  int l = tid&63;
  float acc[NB];
  #pragma unroll
  for(int b=0;b<NB;b++) acc[b]=0.f;
  for(int h=0;h<2;h++){
    for(int i=tid;i<8*1024;i+=256){ int bb=i>>10, k=i&1023; sm[i]=att1_sm[(long)(h*8+bb)*NK1+k]; }
    __syncthreads();
    if (m < MPROJ){
      for(int k=l;k<1024;k+=64){
        float w = getel(proj_w, (long)m*NK1+k, f);
        #pragma unroll
        for(int bb=0;bb<8;bb++) acc[h*8+bb] += w * sm[bb*1024+k];
      }
    }
    __syncthreads();
  }
  if (m >= MPROJ) return;
  if(l==0){
    float wt = getel(proj_w, (long)m*NK1 + 1024, f);
    #pragma unroll
    for(int b=0;b<NB;b++) acc[b] += wt * att1_sm[(long)b*NK1 + 1024];
  }
  #pragma unroll
  for(int b=0;b<NB;b++) acc[b]=wsum(acc[b]);
  if(l==0){
    float pb = getel(proj_b, m, f);
    #pragma unroll
    for(int b=0;b<NB;b++) att1w[(long)b*NK2+m] = 0.3f*(acc[b]+pb);
  }
}

// ---- main pass: one read of x0. Per key k>=1:
//   l2 = clamp(q2p.row/32); e=exp(l2); s1 += att1w[k]*row; s2 += e*row; Z += e
__global__ __launch_bounds__(256) void att2_pass_kernel(const void* __restrict__ x0,
    const float* __restrict__ q2p, const float* __restrict__ att1w,
    float* __restrict__ s1, float* __restrict__ s2, float* __restrict__ Zacc,
    const int* __restrict__ flagp){
  __shared__ float ls[4][1024];
  __shared__ float zs[4];
  int f = flagp[0];
  int b = blockIdx.y;
  int w = threadIdx.x>>6, l = threadIdx.x&63;
  float qf[16];
  {
    const float* qp = q2p + (long)b*DL;
    #pragma unroll
    for(int j=0;j<8;j++){ qf[j]=qp[l*8+j]; qf[8+j]=qp[512+l*8+j]; }
  }
  float af1[16], af2[16];
  #pragma unroll
  for(int j=0;j<16;j++){ af1[j]=0.f; af2[j]=0.f; }
  float zacc=0.f;
  int kbase = blockIdx.x*64 + w*16;
  int nk = NL - kbase; if (nk > 16) nk = 16; if (nk < 0) nk = 0;
  const float* awp = att1w + (long)b*NK2 + kbase + 1;
  for(int i=0;i<nk;i++){
    float rf[16];
    long rowoff = ((long)b*NL + kbase + i)*DL;
    if (f){
      const float* rp = ((const float*)x0) + rowoff;
      float4 a0 = *(const float4*)(rp + l*8);
      float4 a1 = *(const float4*)(rp + l*8 + 4);
      float4 a2 = *(const float4*)(rp + 512 + l*8);
      float4 a3 = *(const float4*)(rp + 512 + l*8 + 4);
      rf[0]=a0.x; rf[1]=a0.y; rf[2]=a0.z; rf[3]=a0.w;
      rf[4]=a1.x; rf[5]=a1.y; rf[6]=a1.z; rf[7]=a1.w;
      rf[8]=a2.x; rf[9]=a2.y; rf[10]=a2.z; rf[11]=a2.w;
      rf[12]=a3.x; rf[13]=a3.y; rf[14]=a3.z; rf[15]=a3.w;
    } else {
      const u16* rp = ((const u16*)x0) + rowoff;
      uint4 rv0 = *(const uint4*)(rp + l*8);
      uint4 rv1 = *(const uint4*)(rp + 512 + l*8);
      u32 wd[8]={rv0.x,rv0.y,rv0.z,rv0.w,rv1.x,rv1.y,rv1.z,rv1.w};
      #pragma unroll
      for(int q=0;q<8;q++){
        union{u32 u; float x;} ua,ub;
        ua.u = wd[q]<<16; ub.u = wd[q]&0xffff0000u;
        rf[2*q]=ua.x; rf[2*q+1]=ub.x;
      }
    }
    float dp=0.f;
    #pragma unroll
    for(int j=0;j<16;j++) dp += rf[j]*qf[j];
    dp = clamp60(wsum(dp)*(1.f/32.f));
    float e = __expf(dp);
    float aw = awp[i];
    zacc += e;
    #pragma unroll
    for(int j=0;j<16;j++){ af1[j] += aw*rf[j]; af2[j] += e*rf[j]; }
  }
  #pragma unroll
  for(int c=0;c<2;c++)
    #pragma unroll
    for(int j=0;j<8;j++) ls[w][c*512 + l*8 + j] = af1[c*8+j];
  __syncthreads();
  for(int d=threadIdx.x; d<1024; d+=256)
    atomicAdd(&s1[(long)b*DL+d], ls[0][d]+ls[1][d]+ls[2][d]+ls[3][d]);
  __syncthreads();
  #pragma unroll
  for(int c=0;c<2;c++)
    #pragma unroll
    for(int j=0;j<8;j++) ls[w][c*512 + l*8 + j] = af2[c*8+j];
  if(l==0) zs[w]=zacc;
  __syncthreads();
  for(int d=threadIdx.x; d<1024; d+=256)
    atomicAdd(&s2[(long)b*DL+d], ls[0][d]+ls[1][d]+ls[2][d]+ls[3][d]);
  if(threadIdx.x==0) atomicAdd(&Zacc[b], zs[0]+zs[1]+zs[2]+zs[3]);
}

// ---- finalize u[b,:] = s1 + a0*cm + 0.7*(s2 + e0*cm)/(Z + e0) ----
__global__ __launch_bounds__(256) void finalize_u_kernel(const float* __restrict__ cmp,
    const float* __restrict__ q2p, const float* __restrict__ att1w,
    const float* __restrict__ s1, const float* __restrict__ s2,
    const float* __restrict__ Zacc, float* __restrict__ u){
  __shared__ float red[4];
  int b=blockIdx.x, t=threadIdx.x;
  float p=0.f;
  for(int d=t;d<DL;d+=256) p += q2p[(long)b*DL+d]*cmp[(long)b*DL+d];
  float l20 = clamp60(block_sum(p,red)*(1.f/32.f));
  float e0 = __expf(l20);
  float Zf = fmaxf(Zacc[b] + e0, 1e-30f);
  float a0 = att1w[(long)b*NK2];
  float c7 = 0.7f/Zf;
  for(int d=t;d<DL;d+=256){
    float cm = cmp[(long)b*DL+d];
    u[(long)b*DL+d] = s1[(long)b*DL+d] + a0*cm + c7*(s2[(long)b*DL+d] + e0*cm);
  }
}

// ---- broadcast g_s[b] to all 4097 output rows, dtype per flag ----
__global__ __launch_bounds__(256) void broadcast_out_kernel(const float* __restrict__ g_s,
    void* __restrict__ out, const int* __restrict__ flagp){
  int f = flagp[0];
  int b = blockIdx.y;
  int colq = threadIdx.x & 31;   // 32 chunks of 8 elems per 256-elem row
  int rowo = threadIdx.x >> 5;   // 8 rows per block
  int r = blockIdx.x*8 + rowo;
  const float* gp = g_s + (long)b*DS + colq*8;
  float4 ga = *(const float4*)gp;
  float4 gb = *(const float4*)(gp+4);
  if (r >= NL) return;
  long row = (long)b*NL + r;
  if (f){
    float4* op = (float4*)out + row*64 + colq*2;
    op[0]=ga; op[1]=gb;
  } else {
    uint4 pk;
    pk.x = (u32)f2bf(ga.x) | ((u32)f2bf(ga.y)<<16);
    pk.y = (u32)f2bf(ga.z) | ((u32)f2bf(ga.w)<<16);
    pk.z = (u32)f2bf(gb.x) | ((u32)f2bf(gb.y)<<16);
    pk.w = (u32)f2bf(gb.z) | ((u32)f2bf(gb.w)<<16);
    ((uint4*)out)[row*32 + colq] = pk;
  }
}

extern "C" void kernel_launch(void* const* d_in, const int* in_sizes, int n_in,
                              void* d_out, int out_size, void* d_ws, size_t ws_size,
                              hipStream_t stream) {
  const void* x0     = d_in[0];
  const void* x1     = d_in[1];
  const void* x2     = d_in[2];
  const void* f_s_w  = d_in[3];
  const void* f_s_b  = d_in[4];
  const void* f_m_w  = d_in[5];
  const void* f_m_b  = d_in[6];
  const void* Wq1    = d_in[7];
  const void* Wk1    = d_in[8];
  const void* Wq2    = d_in[9];
  const void* Wk2    = d_in[10];
  const void* Wv     = d_in[11];
  const void* proj_w = d_in[12];
  const void* proj_b = d_in[13];
  const void* gs_w   = d_in[14];
  const void* gs_b   = d_in[15];

  float* ws = (float*)d_ws;
  float* cls_s_proj = ws;                      // 16*512
  float* cls_m_proj = cls_s_proj + NB*DM;      // 16*1024
  float* q1v        = cls_m_proj + NB*DL;      // 16*512
  float* q2v        = q1v + NB*DM;             // 16*1024
  float* logits1    = q2v + NB*DL;             // 16*1025 (index 0 unused)
  float* att1_sm    = logits1 + NB*NK1;        // 16*1025
  float* att1w      = att1_sm + NB*NK1;        // 16*4098 (pre-scaled by 0.3)
  float* uvec       = att1w + NB*NK2;          // 16*1024
  float* outv       = uvec + NB*DL;            // 16*1024
  float* g_s        = outv + NB*DL;            // 16*256
  float* q1p        = g_s + NB*DS;             // 16*512   <- zeroed
  float* q2p        = q1p + NB*DM;             // 16*1024  <- zeroed
  float* s1         = q2p + NB*DL;             // 16*1024  <- zeroed
  float* s2         = s1 + NB*DL;              // 16*1024  <- zeroed
  float* Zacc       = s2 + NB*DL;              // 16       <- zeroed
  int*   flag       = (int*)(Zacc + NB);       // 1
  size_t zero_bytes = (size_t)(NB*DM + 3*NB*DL + NB) * sizeof(float);
  hipMemsetAsync(q1p, 0, zero_bytes, stream);

  detect_kernel<<<1,256,0,stream>>>((const u16*)x0, flag);

  // Stage A: cls projections, then q1/q2, then q1p/q2p (transpose matvecs)
  Job ja0{f_s_w, x2, f_s_b, cls_s_proj, DM, DS, (long)NL*DS, 0};
  Job ja1{f_m_w, x1, f_m_b, cls_m_proj, DL, DM, (long)NM_ROWS*DM, 0};
  gemv_n_kernel<<<dim3(256,2),256,0,stream>>>(ja0, ja1, flag);

  Job jb0{Wq1, cls_s_proj, nullptr, q1v, DM, DM, DM, 1};
  Job jb1{Wq2, cls_m_proj, nullptr, q2v, DL, DL, DL, 1};
  gemv_n_kernel<<<dim3(256,2),256,0,stream>>>(jb0, jb1, flag);

  TJob jt0{Wk1, q1v, q1p, DM, DM};
  TJob jt1{Wk2, q2v, q2p, DL, DL};
  gemv_t_kernel<<<dim3(4,16,2),256,0,stream>>>(jt0, jt1, flag);

  // Stage B: att1
  att1_logits_kernel<<<dim3(256,NB),256,0,stream>>>(x1, q1p, logits1, flag);
  att1_softmax_kernel<<<NB,256,0,stream>>>(cls_s_proj, q1p, logits1, att1_sm);
  att1_proj_kernel<<<dim3(1025),256,0,stream>>>(proj_w, proj_b, att1_sm, att1w, flag);

  // Stage C: single pass over x0 — the dominant kernel
  att2_pass_kernel<<<dim3(65,NB),256,0,stream>>>(x0, q2p, att1w, s1, s2, Zacc, flag);

  // Stage D: finalize u, then out = Wv@u, g_s = gs_w@out + gs_b
  finalize_u_kernel<<<NB,256,0,stream>>>(cls_m_proj, q2p, att1w, s1, s2, Zacc, uvec);
  Job jv{Wv, uvec, nullptr, outv, DL, DL, DL, 1};
  gemv_n_kernel<<<dim3(256,1),256,0,stream>>>(jv, jv, flag);
  Job jg{gs_w, outv, gs_b, g_s, DS, DL, DL, 1};
  gemv_n_kernel<<<dim3(64,1),256,0,stream>>>(jg, jg, flag);

  // Stage E: broadcast write (all 4097 rows per batch equal g_s[b])
  broadcast_out_kernel<<<dim3(513,NB),256,0,stream>>>(g_s, d_out, flag);
}

// Round 3
// 678.195 us; speedup vs baseline: 1.0091x; 1.0091x over previous
//
#include <hip/hip_runtime.h>
#include <stdint.h>

typedef unsigned int u32;
typedef unsigned short u16;

#define NB 16
#define NL 4097      // x0 rows per batch (= att2 keys - 1)
#define NM_ROWS 1025 // x1 rows per batch
#define DS 256
#define DM 512
#define DL 1024
#define NK1 1025     // att1 keys
#define NK2 4098     // att2 keys
#define MPROJ 4098   // proj_w output dim

__device__ __forceinline__ float bf2f(u16 h){ union{u32 u; float f;} c; c.u = ((u32)h)<<16; return c.f; }
__device__ __forceinline__ u16 f2bf(float x){ union{float f; u32 u;} c; c.f=x; u32 u=c.u; return (u16)((u + 0x7fffu + ((u>>16)&1u))>>16); }
// dtype-flexible element read: f!=0 -> fp32, else bf16
__device__ __forceinline__ float getel(const void* p, long i, int f){
  return f ? ((const float*)p)[i] : bf2f(((const u16*)p)[i]);
}
__device__ __forceinline__ void unpack8(uint4 v, float* fo){
  u32 w[4]={v.x,v.y,v.z,v.w};
  #pragma unroll
  for(int i=0;i<4;i++){
    union{u32 u; float x;} a,b;
    a.u = w[i]<<16; b.u = w[i]&0xffff0000u;
    fo[2*i]=a.x; fo[2*i+1]=b.x;
  }
}
__device__ __forceinline__ float wsum(float v){
  #pragma unroll
  for(int o=32;o>0;o>>=1) v += __shfl_xor(v,o,64);
  return v;
}
__device__ __forceinline__ float wmaxr(float v){
  #pragma unroll
  for(int o=32;o>0;o>>=1) v = fmaxf(v, __shfl_xor(v,o,64));
  return v;
}
__device__ __forceinline__ float block_sum(float v, volatile float* red){
  v = wsum(v);
  if((threadIdx.x&63)==0) red[threadIdx.x>>6]=v;
  __syncthreads();
  float r = red[0]+red[1]+red[2]+red[3];
  __syncthreads();
  return r;
}
__device__ __forceinline__ float block_max(float v, volatile float* red){
  v = wmaxr(v);
  if((threadIdx.x&63)==0) red[threadIdx.x>>6]=v;
  __syncthreads();
  float r = fmaxf(fmaxf(red[0],red[1]),fmaxf(red[2],red[3]));
  __syncthreads();
  return r;
}
__device__ __forceinline__ float clamp60(float x){ return fminf(fmaxf(x,-60.f),60.f); }

// ---- dtype detection: bf16 N(0,1) data -> max|bf16(u16)| ~ 5; fp32 bits read
// as u16 halves -> random low halves decode to huge bf16 values w.h.p.
__global__ __launch_bounds__(256) void detect_kernel(const u16* __restrict__ x0, int* __restrict__ flag){
  __shared__ float red[256];
  float mx=0.f;
  for(int i=threadIdx.x;i<4096;i+=256){
    float v = fabsf(bf2f(x0[i]));
    if (v==v) mx = fmaxf(mx, v);  // skip NaN
  }
  red[threadIdx.x]=mx; __syncthreads();
  if(threadIdx.x==0){
    float m=0.f;
    for(int i=0;i<256;i++) m=fmaxf(m,red[i]);
    flag[0] = (m>1e3f)?1:0;
  }
}

// ---- batched matvec: out[b,m] = bias[m] + sum_d W[m,d]*x[b,d] ----
// wave per m, 16 batches per wave. x staged in LDS in <=32KB chunks.
struct Job {
  const void* W; const void* x; const void* bias; float* out;
  int M, D; long xstride; int xinws;  // xinws: x is dense fp32 in ws
};

__global__ __launch_bounds__(256) void gemv_n_kernel(Job j0, Job j1, const int* __restrict__ flagp){
  Job j = (blockIdx.y==0)? j0 : j1;
  if ((int)(blockIdx.x*4) >= j.M) return;   // block-uniform early-out (before barriers)
  int f = flagp[0];
  __shared__ float xs[NB*512];
  int tid = threadIdx.x;
  int m = blockIdx.x*4 + (tid>>6);
  int l = tid & 63;
  float acc[NB];
  #pragma unroll
  for(int b=0;b<NB;b++) acc[b]=0.f;
  for(int c0=0;c0<j.D;c0+=512){
    int cl = j.D-c0; if (cl>512) cl=512;
    for(int i=tid;i<NB*cl;i+=256){
      int b=i/cl, d=i-b*cl;
      float v;
      if (j.xinws) v = ((const float*)j.x)[(long)b*j.D + c0 + d];
      else         v = getel(j.x, (long)b*j.xstride + c0 + d, f);
      xs[i]=v;
    }
    __syncthreads();
    if (m < j.M){
      for(int d=l; d<cl; d+=64){
        float w = getel(j.W, (long)m*j.D + c0 + d, f);
        #pragma unroll
        for(int b=0;b<NB;b++) acc[b] += w*xs[b*cl+d];
      }
    }
    __syncthreads();
  }
  if (m >= j.M) return;
  #pragma unroll
  for(int b=0;b<NB;b++) acc[b]=wsum(acc[b]);
  if(l==0){
    float bv = j.bias ? getel(j.bias, m, f) : 0.f;
    #pragma unroll
    for(int b=0;b<NB;b++) j.out[(long)b*j.M+m]=acc[b]+bv;
  }
}

// ---- transpose matvec: out[b,d] += sum_m W[m,d]*x[b,m]  (out pre-zeroed) ----
struct TJob { const void* W; const float* x; float* out; int M, D; };

__global__ __launch_bounds__(256) void gemv_t_kernel(TJob j0, TJob j1, const int* __restrict__ flagp){
  TJob j = (blockIdx.z==0)? j0 : j1;
  int f = flagp[0];
  if ((int)(blockIdx.x*256) >= j.D) return;   // block-uniform guards (before any barrier)
  int m0 = blockIdx.y*64;
  if (m0 >= j.M) return;
  __shared__ float xs[NB*64];
  int d = blockIdx.x*256 + threadIdx.x;
  for(int i=threadIdx.x;i<NB*64;i+=256){ int b=i>>6, mm=i&63; xs[i]=j.x[(long)b*j.M+m0+mm]; }
  __syncthreads();
  float acc[NB];
  #pragma unroll
  for(int b=0;b<NB;b++) acc[b]=0.f;
  for(int mm=0;mm<64;++mm){
    float w = getel(j.W, (long)(m0+mm)*j.D + d, f);
    #pragma unroll
    for(int b=0;b<NB;b++) acc[b] += w*xs[b*64+mm];
  }
  #pragma unroll
  for(int b=0;b<NB;b++) atomicAdd(&j.out[(long)b*j.D+d], acc[b]);
}

// ---- att1 logits for keys 1..1024 (p_m rows of x1): logits1[b,k] = q1p.x1row/22 ----
// D=512 = 64 lanes x 8: one uint4 (bf16) / two float4 (fp32) per lane.
__global__ __launch_bounds__(256) void att1_logits_kernel(const void* __restrict__ x1,
    const float* __restrict__ q1p, float* __restrict__ logits1, const int* __restrict__ flagp){
  int f = flagp[0];
  int b = blockIdx.y;
  int k = blockIdx.x*4 + (threadIdx.x>>6) + 1;
  if (k > 1024) return;
  int l = threadIdx.x & 63;
  long rbase = ((long)b*NM_ROWS + k)*DM + l*8;
  float rf[8];
  if (f){
    const float* rp = (const float*)x1 + rbase;
    float4 a0 = *(const float4*)rp;
    float4 a1 = *(const float4*)(rp+4);
    rf[0]=a0.x; rf[1]=a0.y; rf[2]=a0.z; rf[3]=a0.w;
    rf[4]=a1.x; rf[5]=a1.y; rf[6]=a1.z; rf[7]=a1.w;
  } else {
    uint4 rv = *(const uint4*)((const u16*)x1 + rbase);
    unpack8(rv, rf);
  }
  const float* qp = q1p + (long)b*DM + l*8;
  float s = rf[0]*qp[0]+rf[1]*qp[1]+rf[2]*qp[2]+rf[3]*qp[3]
          + rf[4]*qp[4]+rf[5]*qp[5]+rf[6]*qp[6]+rf[7]*qp[7];
  s = wsum(s);
  if(l==0) logits1[(long)b*NK1 + k] = s * (1.f/22.f);
}

// ---- att1 softmax (one block per batch); key0 logit = q1p.cls_s_proj/22 ----
__global__ __launch_bounds__(256) void att1_softmax_kernel(const float* __restrict__ csp,
    const float* __restrict__ q1p, const float* __restrict__ logits1, float* __restrict__ att1_sm){
  __shared__ float red[4];
  int b=blockIdx.x, t=threadIdx.x;
  float p=0.f;
  for(int d=t;d<DM;d+=256) p += q1p[(long)b*DM+d]*csp[(long)b*DM+d];
  float l0 = block_sum(p, red) * (1.f/22.f);
  float mx = l0;
  for(int k=1+t;k<NK1;k+=256) mx = fmaxf(mx, logits1[(long)b*NK1+k]);
  mx = block_max(mx, red);
  float s=0.f;
  for(int k=t;k<NK1;k+=256){
    float lg = (k==0)? l0 : logits1[(long)b*NK1+k];
    float e = __expf(clamp60(lg-mx));
    att1_sm[(long)b*NK1+k]=e;
    s+=e;
  }
  s = block_sum(s, red);
  float inv = 1.f/fmaxf(s,1e-30f);
  for(int k=t;k<NK1;k+=256) att1_sm[(long)b*NK1+k]*=inv;
}

// ---- att1 projection: att1w[b,m] = 0.3*(proj_b[m] + sum_k att1_sm[b,k]*proj_w[m,k]) ----
__global__ __launch_bounds__(256) void att1_proj_kernel(const void* __restrict__ proj_w,
    const void* __restrict__ proj_b, const float* __restrict__ att1_sm, float* __restrict__ att1w,
    const int* __restrict__ flagp){
  int f = flagp[0];
  __shared__ float sm[8*1024];   // 32KB: 8 batches at a time
  int tid=threadIdx.x;
  int m = blockIdx.x*4 + (tid>>6);
  int l = tid&63;
  float acc[NB];
  #pragma unroll
  for(int b=0;b<NB;b++) acc[b]=0.f;
  for(int h=0;h<2;h++){
    for(int i=tid;i<8*1024;i+=256){ int bb=i>>10, k=i&1023; sm[i]=att1_sm[(long)(h*8+bb)*NK1+k]; }
    __syncthreads();
    if (m < MPROJ){
      for(int k=l;k<1024;k+=64){
        float w = getel(proj_w, (long)m*NK1+k, f);
        #pragma unroll
        for(int bb=0;bb<8;bb++) acc[h*8+bb] += w * sm[bb*1024+k];
      }
    }
    __syncthreads();
  }
  if (m >= MPROJ) return;
  if(l==0){
    float wt = getel(proj_w, (long)m*NK1 + 1024, f);
    #pragma unroll
    for(int b=0;b<NB;b++) acc[b] += wt * att1_sm[(long)b*NK1 + 1024];
  }
  #pragma unroll
  for(int b=0;b<NB;b++) acc[b]=wsum(acc[b]);
  if(l==0){
    float pb = getel(proj_b, m, f);
    #pragma unroll
    for(int b=0;b<NB;b++) att1w[(long)b*NK2+m] = 0.3f*(acc[b]+pb);
  }
}

// ---- main pass: one read of x0. Per key k>=1:
//   l2 = clamp(q2p.row/32); e=exp(l2); s1 += att1w[k]*row; s2 += e*row; Z += e
__global__ __launch_bounds__(256) void att2_pass_kernel(const void* __restrict__ x0,
    const float* __restrict__ q2p, const float* __restrict__ att1w,
    float* __restrict__ s1, float* __restrict__ s2, float* __restrict__ Zacc,
    const int* __restrict__ flagp){
  __shared__ float ls[4][1024];
  __shared__ float zs[4];
  int f = flagp[0];
  int b = blockIdx.y;
  int w = threadIdx.x>>6, l = threadIdx.x&63;
  float qf[16];
  {
    const float* qp = q2p + (long)b*DL;
    #pragma unroll
    for(int j=0;j<8;j++){ qf[j]=qp[l*8+j]; qf[8+j]=qp[512+l*8+j]; }
  }
  float af1[16], af2[16];
  #pragma unroll
  for(int j=0;j<16;j++){ af1[j]=0.f; af2[j]=0.f; }
  float zacc=0.f;
  int kbase = blockIdx.x*64 + w*16;
  int nk = NL - kbase; if (nk > 16) nk = 16; if (nk < 0) nk = 0;
  const float* awp = att1w + (long)b*NK2 + kbase + 1;
  for(int i=0;i<nk;i++){
    float rf[16];
    long rowoff = ((long)b*NL + kbase + i)*DL;
    if (f){
      const float* rp = ((const float*)x0) + rowoff;
      float4 a0 = *(const float4*)(rp + l*8);
      float4 a1 = *(const float4*)(rp + l*8 + 4);
      float4 a2 = *(const float4*)(rp + 512 + l*8);
      float4 a3 = *(const float4*)(rp + 512 + l*8 + 4);
      rf[0]=a0.x; rf[1]=a0.y; rf[2]=a0.z; rf[3]=a0.w;
      rf[4]=a1.x; rf[5]=a1.y; rf[6]=a1.z; rf[7]=a1.w;
      rf[8]=a2.x; rf[9]=a2.y; rf[10]=a2.z; rf[11]=a2.w;
      rf[12]=a3.x; rf[13]=a3.y; rf[14]=a3.z; rf[15]=a3.w;
    } else {
      const u16* rp = ((const u16*)x0) + rowoff;
      uint4 rv0 = *(const uint4*)(rp + l*8);
      uint4 rv1 = *(const uint4*)(rp + 512 + l*8);
      u32 wd[8]={rv0.x,rv0.y,rv0.z,rv0.w,rv1.x,rv1.y,rv1.z,rv1.w};
      #pragma unroll
      for(int q=0;q<8;q++){
        union{u32 u; float x;} ua,ub;
        ua.u = wd[q]<<16; ub.u = wd[q]&0xffff0000u;
        rf[2*q]=ua.x; rf[2*q+1]=ub.x;
      }
    }
    float dp=0.f;
    #pragma unroll
    for(int j=0;j<16;j++) dp += rf[j]*qf[j];
    dp = clamp60(wsum(dp)*(1.f/32.f));
    float e = __expf(dp);
    float aw = awp[i];
    zacc += e;
    #pragma unroll
    for(int j=0;j<16;j++){ af1[j] += aw*rf[j]; af2[j] += e*rf[j]; }
  }
  #pragma unroll
  for(int c=0;c<2;c++)
    #pragma unroll
    for(int j=0;j<8;j++) ls[w][c*512 + l*8 + j] = af1[c*8+j];
  __syncthreads();
  for(int d=threadIdx.x; d<1024; d+=256)
    atomicAdd(&s1[(long)b*DL+d], ls[0][d]+ls[1][d]+ls[2][d]+ls[3][d]);
  __syncthreads();
  #pragma unroll
  for(int c=0;c<2;c++)
    #pragma unroll
    for(int j=0;j<8;j++) ls[w][c*512 + l*8 + j] = af2[c*8+j];
  if(l==0) zs[w]=zacc;
  __syncthreads();
  for(int d=threadIdx.x; d<1024; d+=256)
    atomicAdd(&s2[(long)b*DL+d], ls[0][d]+ls[1][d]+ls[2][d]+ls[3][d]);
  if(threadIdx.x==0) atomicAdd(&Zacc[b], zs[0]+zs[1]+zs[2]+zs[3]);
}

// ---- finalize u[b,:] = s1 + a0*cm + 0.7*(s2 + e0*cm)/(Z + e0) ----
__global__ __launch_bounds__(256) void finalize_u_kernel(const float* __restrict__ cmp,
    const float* __restrict__ q2p, const float* __restrict__ att1w,
    const float* __restrict__ s1, const float* __restrict__ s2,
    const float* __restrict__ Zacc, float* __restrict__ u){
  __shared__ float red[4];
  int b=blockIdx.x, t=threadIdx.x;
  float p=0.f;
  for(int d=t;d<DL;d+=256) p += q2p[(long)b*DL+d]*cmp[(long)b*DL+d];
  float l20 = clamp60(block_sum(p,red)*(1.f/32.f));
  float e0 = __expf(l20);
  float Zf = fmaxf(Zacc[b] + e0, 1e-30f);
  float a0 = att1w[(long)b*NK2];
  float c7 = 0.7f/Zf;
  for(int d=t;d<DL;d+=256){
    float cm = cmp[(long)b*DL+d];
    u[(long)b*DL+d] = s1[(long)b*DL+d] + a0*cm + c7*(s2[(long)b*DL+d] + e0*cm);
  }
}

// ---- broadcast g_s[b] to all 4097 output rows, dtype per flag ----
__global__ __launch_bounds__(256) void broadcast_out_kernel(const float* __restrict__ g_s,
    void* __restrict__ out, const int* __restrict__ flagp){
  int f = flagp[0];
  int b = blockIdx.y;
  int colq = threadIdx.x & 31;   // 32 chunks of 8 elems per 256-elem row
  int rowo = threadIdx.x >> 5;   // 8 rows per block
  int r = blockIdx.x*8 + rowo;
  const float* gp = g_s + (long)b*DS + colq*8;
  float4 ga = *(const float4*)gp;
  float4 gb = *(const float4*)(gp+4);
  if (r >= NL) return;
  long row = (long)b*NL + r;
  if (f){
    float4* op = (float4*)out + row*64 + colq*2;
    op[0]=ga; op[1]=gb;
  } else {
    uint4 pk;
    pk.x = (u32)f2bf(ga.x) | ((u32)f2bf(ga.y)<<16);
    pk.y = (u32)f2bf(ga.z) | ((u32)f2bf(ga.w)<<16);
    pk.z = (u32)f2bf(gb.x) | ((u32)f2bf(gb.y)<<16);
    pk.w = (u32)f2bf(gb.z) | ((u32)f2bf(gb.w)<<16);
    ((uint4*)out)[row*32 + colq] = pk;
  }
}

extern "C" void kernel_launch(void* const* d_in, const int* in_sizes, int n_in,
                              void* d_out, int out_size, void* d_ws, size_t ws_size,
                              hipStream_t stream) {
  const void* x0     = d_in[0];
  const void* x1     = d_in[1];
  const void* x2     = d_in[2];
  const void* f_s_w  = d_in[3];
  const void* f_s_b  = d_in[4];
  const void* f_m_w  = d_in[5];
  const void* f_m_b  = d_in[6];
  const void* Wq1    = d_in[7];
  const void* Wk1    = d_in[8];
  const void* Wq2    = d_in[9];
  const void* Wk2    = d_in[10];
  const void* Wv     = d_in[11];
  const void* proj_w = d_in[12];
  const void* proj_b = d_in[13];
  const void* gs_w   = d_in[14];
  const void* gs_b   = d_in[15];

  float* ws = (float*)d_ws;
  float* cls_s_proj = ws;                      // 16*512
  float* cls_m_proj = cls_s_proj + NB*DM;      // 16*1024
  float* q1v        = cls_m_proj + NB*DL;      // 16*512
  float* q2v        = q1v + NB*DM;             // 16*1024
  float* logits1    = q2v + NB*DL;             // 16*1025 (index 0 unused)
  float* att1_sm    = logits1 + NB*NK1;        // 16*1025
  float* att1w      = att1_sm + NB*NK1;        // 16*4098 (pre-scaled by 0.3)
  float* uvec       = att1w + NB*NK2;          // 16*1024
  float* outv       = uvec + NB*DL;            // 16*1024
  float* g_s        = outv + NB*DL;            // 16*256
  float* q1p        = g_s + NB*DS;             // 16*512   <- zeroed
  float* q2p        = q1p + NB*DM;             // 16*1024  <- zeroed
  float* s1         = q2p + NB*DL;             // 16*1024  <- zeroed
  float* s2         = s1 + NB*DL;              // 16*1024  <- zeroed
  float* Zacc       = s2 + NB*DL;              // 16       <- zeroed
  int*   flag       = (int*)(Zacc + NB);       // 1
  size_t zero_bytes = (size_t)(NB*DM + 3*NB*DL + NB) * sizeof(float);
  hipMemsetAsync(q1p, 0, zero_bytes, stream);

  detect_kernel<<<1,256,0,stream>>>((const u16*)x0, flag);

  // Stage A: cls projections, then q1/q2, then q1p/q2p (transpose matvecs)
  Job ja0{f_s_w, x2, f_s_b, cls_s_proj, DM, DS, (long)NL*DS, 0};
  Job ja1{f_m_w, x1, f_m_b, cls_m_proj, DL, DM, (long)NM_ROWS*DM, 0};
  gemv_n_kernel<<<dim3(256,2),256,0,stream>>>(ja0, ja1, flag);

  Job jb0{Wq1, cls_s_proj, nullptr, q1v, DM, DM, DM, 1};
  Job jb1{Wq2, cls_m_proj, nullptr, q2v, DL, DL, DL, 1};
  gemv_n_kernel<<<dim3(256,2),256,0,stream>>>(jb0, jb1, flag);

  TJob jt0{Wk1, q1v, q1p, DM, DM};
  TJob jt1{Wk2, q2v, q2p, DL, DL};
  gemv_t_kernel<<<dim3(4,16,2),256,0,stream>>>(jt0, jt1, flag);

  // Stage B: att1
  att1_logits_kernel<<<dim3(256,NB),256,0,stream>>>(x1, q1p, logits1, flag);
  att1_softmax_kernel<<<NB,256,0,stream>>>(cls_s_proj, q1p, logits1, att1_sm);
  att1_proj_kernel<<<dim3(1025),256,0,stream>>>(proj_w, proj_b, att1_sm, att1w, flag);

  // Stage C: single pass over x0 — the dominant kernel
  att2_pass_kernel<<<dim3(65,NB),256,0,stream>>>(x0, q2p, att1w, s1, s2, Zacc, flag);

  // Stage D: finalize u, then out = Wv@u, g_s = gs_w@out + gs_b
  finalize_u_kernel<<<NB,256,0,stream>>>(cls_m_proj, q2p, att1w, s1, s2, Zacc, uvec);
  Job jv{Wv, uvec, nullptr, outv, DL, DL, DL, 1};
  gemv_n_kernel<<<dim3(256,1),256,0,stream>>>(jv, jv, flag);
  Job jg{gs_w, outv, gs_b, g_s, DS, DL, DL, 1};
  gemv_n_kernel<<<dim3(64,1),256,0,stream>>>(jg, jg, flag);

  // Stage E: broadcast write (all 4097 rows per batch equal g_s[b])
  broadcast_out_kernel<<<dim3(513,NB),256,0,stream>>>(g_s, d_out, flag);
}